// Round 1
// baseline (1202.912 us; speedup 1.0000x reference)
//
#include <hip/hip_runtime.h>

// GCNII: N=100000 nodes, E=1000000 edges, F=64 features throughout.
// Inputs: x[N*64] f32, edge_index[2*E] i32 (row=src at [0..E), col=dst at [E..2E)),
// Ws[(L-1)*64*64], W_gcn[64*64], b_gcn[64], W1[64*4], b1[4], W2[64*3], b2[3].
// Output: concat(out1 [N*4], out2 [N*3], h [N*64]) fp32.

__global__ void deg_kernel(const int* __restrict__ col, float* __restrict__ deg, int E) {
    int e = blockIdx.x * blockDim.x + threadIdx.x;
    if (e < E) atomicAdd(&deg[col[e]], 1.0f);
}

__global__ void dinv_kernel(float* __restrict__ deg, int n) {
    int v = blockIdx.x * blockDim.x + threadIdx.x;
    if (v < n) deg[v] = rsqrtf(deg[v] + 1.0f);  // +1 = self-loop
}

// p[col] += dinv[row]*dinv[col] * x[row]  (edge part only; self-loop folded later)
// one wave (64 lanes) per edge: lane = feature index
__global__ void prop_kernel(const int* __restrict__ ei, const float* __restrict__ dinv,
                            const float* __restrict__ x, float* __restrict__ p, int E) {
    int tid = blockIdx.x * blockDim.x + threadIdx.x;
    int e = tid >> 6;
    int f = tid & 63;
    if (e < E) {
        int r = ei[e];
        int c = ei[E + e];
        float w = dinv[r] * dinv[c];
        atomicAdd(&p[(size_t)c * 64 + f], w * x[(size_t)r * 64 + f]);
    }
}

// y[v][j] = act( sum_k t[v][k] * W[k][j] )
// COMBINE: t = 0.9*(p + dinv^2*x) + 0.1*x, act = relu   (GCN2Conv layer)
// else:    t = x, act = identity                        (x @ W_gcn)
// lane j holds W[:,j] in 64 VGPRs; activations broadcast via LDS float4 reads.
template<bool COMBINE>
__global__ __launch_bounds__(256) void mm_kernel(
        const float* __restrict__ p, const float* __restrict__ x,
        const float* __restrict__ dinv, const float* __restrict__ W,
        float* __restrict__ y, int n) {
    __shared__ __align__(16) float st[4][64];
    int wid = threadIdx.x >> 6;
    int lane = threadIdx.x & 63;
    float wreg[64];
#pragma unroll
    for (int k = 0; k < 64; ++k) wreg[k] = W[k * 64 + lane];
    int ntiles = (n + 3) >> 2;
    for (int tile = blockIdx.x; tile < ntiles; tile += gridDim.x) {
        int v = tile * 4 + wid;
        float t = 0.0f;
        if (v < n) {
            float xv = x[(size_t)v * 64 + lane];
            if (COMBINE) {
                float d = dinv[v];
                t = 0.9f * (p[(size_t)v * 64 + lane] + d * d * xv) + 0.1f * xv;
            } else {
                t = xv;
            }
        }
        __syncthreads();          // protect previous iteration's reads
        st[wid][lane] = t;
        __syncthreads();
        if (v < n) {
            float acc = 0.0f;
#pragma unroll
            for (int k4 = 0; k4 < 16; ++k4) {
                float4 tt = *(const float4*)&st[wid][k4 * 4];
                acc = fmaf(tt.x, wreg[k4 * 4 + 0], acc);
                acc = fmaf(tt.y, wreg[k4 * 4 + 1], acc);
                acc = fmaf(tt.z, wreg[k4 * 4 + 2], acc);
                acc = fmaf(tt.w, wreg[k4 * 4 + 3], acc);
            }
            y[(size_t)v * 64 + lane] = COMBINE ? fmaxf(acc, 0.0f) : acc;
        }
    }
}

// h = p + dinv^2*xw + b_gcn;  out1 = h@W1+b1;  out2 = h@W2+b2;  also emit h.
// one wave per node (lane = feature); lanes 0..6 then do the 7 tiny dots.
__global__ __launch_bounds__(256) void heads_kernel(
        const float* __restrict__ p, const float* __restrict__ xw,
        const float* __restrict__ dinv, const float* __restrict__ bg,
        const float* __restrict__ W1, const float* __restrict__ b1,
        const float* __restrict__ W2, const float* __restrict__ b2,
        float* __restrict__ out, int n) {
    __shared__ float hs[4][65];
    int wid = threadIdx.x >> 6;
    int lane = threadIdx.x & 63;
    int v = blockIdx.x * 4 + wid;
    float h = 0.0f;
    if (v < n) {
        float d = dinv[v];
        h = p[(size_t)v * 64 + lane] + d * d * xw[(size_t)v * 64 + lane] + bg[lane];
        out[(size_t)7 * n + (size_t)v * 64 + lane] = h;  // h region at offset 7N
    }
    hs[wid][lane] = h;
    __syncthreads();
    if (v < n && lane < 7) {
        if (lane < 4) {
            float s = b1[lane];
#pragma unroll
            for (int k = 0; k < 64; ++k) s = fmaf(hs[wid][k], W1[k * 4 + lane], s);
            out[(size_t)v * 4 + lane] = s;
        } else {
            int j = lane - 4;
            float s = b2[j];
#pragma unroll
            for (int k = 0; k < 64; ++k) s = fmaf(hs[wid][k], W2[k * 3 + j], s);
            out[(size_t)4 * n + (size_t)v * 3 + j] = s;
        }
    }
}

extern "C" void kernel_launch(void* const* d_in, const int* in_sizes, int n_in,
                              void* d_out, int out_size, void* d_ws, size_t ws_size,
                              hipStream_t stream) {
    const float* x     = (const float*)d_in[0];
    const int*   ei    = (const int*)d_in[1];
    const float* Ws    = (const float*)d_in[2];
    const float* W_gcn = (const float*)d_in[3];
    const float* b_gcn = (const float*)d_in[4];
    const float* W1    = (const float*)d_in[5];
    const float* b1    = (const float*)d_in[6];
    const float* W2    = (const float*)d_in[7];
    const float* b2    = (const float*)d_in[8];
    float* out = (float*)d_out;

    const int N = in_sizes[0] / 64;
    const int E = in_sizes[1] / 2;
    const int NLAYERS = in_sizes[2] / 4096;  // L-1 = 3

    // workspace layout (floats): dinv[N] | p[N*64] | bufA[N*64] | bufB[N*64]
    float* dinv = (float*)d_ws;
    float* p    = dinv + N;
    float* bufA = p + (size_t)N * 64;
    float* bufB = bufA + (size_t)N * 64;

    const int TPB = 256;
    const int mm_grid = 2560;  // grid-stride over node tiles of 4

    // degree -> dinv
    hipMemsetAsync(dinv, 0, (size_t)N * sizeof(float), stream);
    deg_kernel<<<(E + TPB - 1) / TPB, TPB, 0, stream>>>(ei + E, dinv, E);
    dinv_kernel<<<(N + TPB - 1) / TPB, TPB, 0, stream>>>(dinv, N);

    const int prop_grid = (int)(((size_t)E * 64 + TPB - 1) / TPB);
    const int node_grid = (N + 3) / 4;

    // GCN2Conv layers
    const float* xcur = x;
    float* ybuf = bufA;
    for (int i = 0; i < NLAYERS; ++i) {
        hipMemsetAsync(p, 0, (size_t)N * 64 * sizeof(float), stream);
        prop_kernel<<<prop_grid, TPB, 0, stream>>>(ei, dinv, xcur, p, E);
        mm_kernel<true><<<mm_grid, TPB, 0, stream>>>(p, xcur, dinv, Ws + (size_t)i * 4096,
                                                     ybuf, N);
        xcur = ybuf;
        ybuf = (ybuf == bufA) ? bufB : bufA;
    }

    // GCNConv: xw = x @ W_gcn ; h = propagate(xw) + dinv^2*xw + b_gcn ; heads
    float* xw = ybuf;  // the buffer not currently holding xcur
    mm_kernel<false><<<mm_grid, TPB, 0, stream>>>(nullptr, xcur, dinv, W_gcn, xw, N);
    hipMemsetAsync(p, 0, (size_t)N * 64 * sizeof(float), stream);
    prop_kernel<<<prop_grid, TPB, 0, stream>>>(ei, dinv, xw, p, E);
    heads_kernel<<<node_grid, TPB, 0, stream>>>(p, xw, dinv, b_gcn, W1, b1, W2, b2, out, N);
}

// Round 2
// 572.769 us; speedup vs baseline: 2.1002x; 2.1002x over previous
//
#include <hip/hip_runtime.h>

// GCNII fused: CSR build (counting sort by dst) + fused gather/combine/matmul layers.
// N=100000, E=1000000, F=64.
// Output: concat(out1 [N*4], out2 [N*3], h [N*64]) fp32.

#define TPB 256

// ---- degree count (int) ----
__global__ void deg_count_kernel(const int* __restrict__ col, int* __restrict__ degi, int E) {
    int e = blockIdx.x * blockDim.x + threadIdx.x;
    if (e < E) atomicAdd(&degi[col[e]], 1);
}

__global__ void dinv_kernel(const int* __restrict__ degi, float* __restrict__ dinv, int n) {
    int v = blockIdx.x * blockDim.x + threadIdx.x;
    if (v < n) dinv[v] = rsqrtf((float)degi[v] + 1.0f);  // +1 = self-loop
}

// ---- exclusive scan of degi -> rowptr (3-phase, chunks of 1024) ----
__global__ void scan_block_kernel(const int* __restrict__ degi, int* __restrict__ rowptr,
                                  int* __restrict__ blksum, int n) {
    __shared__ int s[256];
    int base = blockIdx.x * 1024;
    int t = threadIdx.x;
    int v[4]; int sum = 0;
#pragma unroll
    for (int i = 0; i < 4; ++i) {
        int idx = base + t * 4 + i;
        v[i] = (idx < n) ? degi[idx] : 0;
        sum += v[i];
    }
    s[t] = sum;
    __syncthreads();
    for (int off = 1; off < 256; off <<= 1) {
        int val = (t >= off) ? s[t - off] : 0;
        __syncthreads();
        s[t] += val;
        __syncthreads();
    }
    int excl = s[t] - sum;
    if (t == 255) blksum[blockIdx.x] = s[255];
    int run = excl;
#pragma unroll
    for (int i = 0; i < 4; ++i) {
        int idx = base + t * 4 + i;
        if (idx < n) rowptr[idx] = run;
        run += v[i];
    }
}

__global__ void scan_top_kernel(int* __restrict__ blksum, int* __restrict__ blkoff, int nblk) {
    __shared__ int s[256];
    int t = threadIdx.x;
    int mine = (t < nblk) ? blksum[t] : 0;
    s[t] = mine;
    __syncthreads();
    for (int off = 1; off < 256; off <<= 1) {
        int val = (t >= off) ? s[t - off] : 0;
        __syncthreads();
        s[t] += val;
        __syncthreads();
    }
    if (t < nblk) blkoff[t] = s[t] - mine;  // exclusive
}

__global__ void scan_add_kernel(int* __restrict__ rowptr, int* __restrict__ cursor,
                                const int* __restrict__ blkoff, int n) {
    int idx = blockIdx.x * blockDim.x + threadIdx.x;
    if (idx < n) {
        int val = rowptr[idx] + blkoff[idx >> 10];
        rowptr[idx] = val;
        cursor[idx] = val;
    }
}

// ---- scatter edges into dst-sorted buckets: srt[pos] = {row, dinv[r]*dinv[c]} ----
__global__ void scatter_kernel(const int* __restrict__ ei, const float* __restrict__ dinv,
                               int* __restrict__ cursor, int2* __restrict__ srt, int E) {
    int e = blockIdx.x * blockDim.x + threadIdx.x;
    if (e < E) {
        int r = ei[e];
        int c = ei[E + e];
        int pos = atomicAdd(&cursor[c], 1);
        int2 rec;
        rec.x = r;
        rec.y = __float_as_int(dinv[r] * dinv[c]);
        srt[pos] = rec;
    }
}

// ---- fused GCN2Conv layer: y = relu( (0.9*(A_hat x) + 0.1*x) @ W ) ----
// one wave per node (grid-stride); lane = feature. Gather over CSR, combine,
// then intra-wave LDS broadcast for the 64x64 matmul (W columns in VGPRs).
__global__ __launch_bounds__(256) void layer_kernel(
        const int* __restrict__ rowptr, const int* __restrict__ degi,
        const int2* __restrict__ srt, const float* __restrict__ x,
        const float* __restrict__ dinv, const float* __restrict__ W,
        float* __restrict__ y, int n) {
    __shared__ __align__(16) float st[4][64];
    int wid = threadIdx.x >> 6;
    int lane = threadIdx.x & 63;
    float wreg[64];
#pragma unroll
    for (int k = 0; k < 64; ++k) wreg[k] = W[k * 64 + lane];
    int stride = gridDim.x * 4;
    for (int v = blockIdx.x * 4 + wid; v < n; v += stride) {
        int beg = rowptr[v];
        int end = beg + degi[v];
        float acc = 0.0f;
        int e = beg;
        for (; e + 4 <= end; e += 4) {          // 4 independent gathers in flight
            int2 r0 = srt[e], r1 = srt[e + 1], r2 = srt[e + 2], r3 = srt[e + 3];
            float x0 = x[(size_t)r0.x * 64 + lane];
            float x1 = x[(size_t)r1.x * 64 + lane];
            float x2 = x[(size_t)r2.x * 64 + lane];
            float x3 = x[(size_t)r3.x * 64 + lane];
            acc = fmaf(__int_as_float(r0.y), x0, acc);
            acc = fmaf(__int_as_float(r1.y), x1, acc);
            acc = fmaf(__int_as_float(r2.y), x2, acc);
            acc = fmaf(__int_as_float(r3.y), x3, acc);
        }
        for (; e < end; ++e) {
            int2 r = srt[e];
            acc = fmaf(__int_as_float(r.y), x[(size_t)r.x * 64 + lane], acc);
        }
        float xv = x[(size_t)v * 64 + lane];
        float d = dinv[v];
        float t = 0.9f * (acc + d * d * xv) + 0.1f * xv;
        st[wid][lane] = t;
        __builtin_amdgcn_wave_barrier();        // intra-wave LDS exchange, no block sync
        float o = 0.0f;
#pragma unroll
        for (int k4 = 0; k4 < 16; ++k4) {
            float4 tt = *(const float4*)&st[wid][k4 * 4];
            o = fmaf(tt.x, wreg[k4 * 4 + 0], o);
            o = fmaf(tt.y, wreg[k4 * 4 + 1], o);
            o = fmaf(tt.z, wreg[k4 * 4 + 2], o);
            o = fmaf(tt.w, wreg[k4 * 4 + 3], o);
        }
        __builtin_amdgcn_wave_barrier();
        y[(size_t)v * 64 + lane] = fmaxf(o, 0.0f);
    }
}

// ---- plain matmul: y = x @ W (64x64), same intra-wave structure ----
__global__ __launch_bounds__(256) void mm_kernel(
        const float* __restrict__ x, const float* __restrict__ W,
        float* __restrict__ y, int n) {
    __shared__ __align__(16) float st[4][64];
    int wid = threadIdx.x >> 6;
    int lane = threadIdx.x & 63;
    float wreg[64];
#pragma unroll
    for (int k = 0; k < 64; ++k) wreg[k] = W[k * 64 + lane];
    int stride = gridDim.x * 4;
    for (int v = blockIdx.x * 4 + wid; v < n; v += stride) {
        st[wid][lane] = x[(size_t)v * 64 + lane];
        __builtin_amdgcn_wave_barrier();
        float o = 0.0f;
#pragma unroll
        for (int k4 = 0; k4 < 16; ++k4) {
            float4 tt = *(const float4*)&st[wid][k4 * 4];
            o = fmaf(tt.x, wreg[k4 * 4 + 0], o);
            o = fmaf(tt.y, wreg[k4 * 4 + 1], o);
            o = fmaf(tt.z, wreg[k4 * 4 + 2], o);
            o = fmaf(tt.w, wreg[k4 * 4 + 3], o);
        }
        __builtin_amdgcn_wave_barrier();
        y[(size_t)v * 64 + lane] = o;
    }
}

// ---- final: h = gather(xw) + dinv^2*xw + b_gcn; out1 = h@W1+b1; out2 = h@W2+b2 ----
__global__ __launch_bounds__(256) void heads_kernel(
        const int* __restrict__ rowptr, const int* __restrict__ degi,
        const int2* __restrict__ srt, const float* __restrict__ xw,
        const float* __restrict__ dinv, const float* __restrict__ bg,
        const float* __restrict__ W1, const float* __restrict__ b1,
        const float* __restrict__ W2, const float* __restrict__ b2,
        float* __restrict__ out, int n) {
    __shared__ __align__(16) float hs[4][64];
    int wid = threadIdx.x >> 6;
    int lane = threadIdx.x & 63;
    // lane j<4: W1 column j; 4<=j<7: W2 column j-4; else zero
    float wh[64];
    float bias = 0.0f;
#pragma unroll
    for (int k = 0; k < 64; ++k) wh[k] = 0.0f;
    if (lane < 4) {
        for (int k = 0; k < 64; ++k) wh[k] = W1[k * 4 + lane];
        bias = b1[lane];
    } else if (lane < 7) {
        for (int k = 0; k < 64; ++k) wh[k] = W2[k * 3 + (lane - 4)];
        bias = b2[lane - 4];
    }
    int stride = gridDim.x * 4;
    for (int v = blockIdx.x * 4 + wid; v < n; v += stride) {
        int beg = rowptr[v];
        int end = beg + degi[v];
        float acc = 0.0f;
        int e = beg;
        for (; e + 4 <= end; e += 4) {
            int2 r0 = srt[e], r1 = srt[e + 1], r2 = srt[e + 2], r3 = srt[e + 3];
            float x0 = xw[(size_t)r0.x * 64 + lane];
            float x1 = xw[(size_t)r1.x * 64 + lane];
            float x2 = xw[(size_t)r2.x * 64 + lane];
            float x3 = xw[(size_t)r3.x * 64 + lane];
            acc = fmaf(__int_as_float(r0.y), x0, acc);
            acc = fmaf(__int_as_float(r1.y), x1, acc);
            acc = fmaf(__int_as_float(r2.y), x2, acc);
            acc = fmaf(__int_as_float(r3.y), x3, acc);
        }
        for (; e < end; ++e) {
            int2 r = srt[e];
            acc = fmaf(__int_as_float(r.y), xw[(size_t)r.x * 64 + lane], acc);
        }
        float d = dinv[v];
        float h = acc + d * d * xw[(size_t)v * 64 + lane] + bg[lane];
        out[(size_t)7 * n + (size_t)v * 64 + lane] = h;
        hs[wid][lane] = h;
        __builtin_amdgcn_wave_barrier();
        if (lane < 7) {
            float s = bias;
#pragma unroll
            for (int k4 = 0; k4 < 16; ++k4) {
                float4 tt = *(const float4*)&hs[wid][k4 * 4];
                s = fmaf(tt.x, wh[k4 * 4 + 0], s);
                s = fmaf(tt.y, wh[k4 * 4 + 1], s);
                s = fmaf(tt.z, wh[k4 * 4 + 2], s);
                s = fmaf(tt.w, wh[k4 * 4 + 3], s);
            }
            if (lane < 4) out[(size_t)v * 4 + lane] = s;
            else          out[(size_t)4 * n + (size_t)v * 3 + (lane - 4)] = s;
        }
        __builtin_amdgcn_wave_barrier();
    }
}

extern "C" void kernel_launch(void* const* d_in, const int* in_sizes, int n_in,
                              void* d_out, int out_size, void* d_ws, size_t ws_size,
                              hipStream_t stream) {
    const float* x     = (const float*)d_in[0];
    const int*   ei    = (const int*)d_in[1];
    const float* Ws    = (const float*)d_in[2];
    const float* W_gcn = (const float*)d_in[3];
    const float* b_gcn = (const float*)d_in[4];
    const float* W1    = (const float*)d_in[5];
    const float* b1    = (const float*)d_in[6];
    const float* W2    = (const float*)d_in[7];
    const float* b2    = (const float*)d_in[8];
    float* out = (float*)d_out;

    const int N = in_sizes[0] / 64;
    const int E = in_sizes[1] / 2;
    const int NLAYERS = in_sizes[2] / 4096;  // L-1 = 3

    // workspace layout:
    // degi[N] | rowptr[N] | cursor[N] | blksum[256] | blkoff[256] (ints)
    // dinv[N] | srt[E] (int2) | bufA[N*64] | bufB[N*64] (floats)
    int*   degi   = (int*)d_ws;
    int*   rowptr = degi + N;
    int*   cursor = rowptr + N;
    int*   blksum = cursor + N;
    int*   blkoff = blksum + 256;
    float* dinv   = (float*)(blkoff + 256);
    int2*  srt    = (int2*)(dinv + N);
    float* bufA   = (float*)(srt + E);
    float* bufB   = bufA + (size_t)N * 64;

    const int nblk = (N + 1023) / 1024;
    const int grid_e = (E + TPB - 1) / TPB;
    const int grid_n = (N + TPB - 1) / TPB;
    const int WGRID = 4096;  // grid-stride, wave-per-node kernels

    // ---- CSR build ----
    hipMemsetAsync(degi, 0, (size_t)N * sizeof(int), stream);
    deg_count_kernel<<<grid_e, TPB, 0, stream>>>(ei + E, degi, E);
    dinv_kernel<<<grid_n, TPB, 0, stream>>>(degi, dinv, N);
    scan_block_kernel<<<nblk, 256, 0, stream>>>(degi, rowptr, blksum, N);
    scan_top_kernel<<<1, 256, 0, stream>>>(blksum, blkoff, nblk);
    scan_add_kernel<<<grid_n, TPB, 0, stream>>>(rowptr, cursor, blkoff, N);
    scatter_kernel<<<grid_e, TPB, 0, stream>>>(ei, dinv, cursor, srt, E);

    // ---- GCN2Conv layers (fused gather+combine+matmul+relu) ----
    const float* xcur = x;
    float* ybuf = bufA;
    for (int i = 0; i < NLAYERS; ++i) {
        layer_kernel<<<WGRID, TPB, 0, stream>>>(rowptr, degi, srt, xcur, dinv,
                                                Ws + (size_t)i * 4096, ybuf, N);
        xcur = ybuf;
        ybuf = (ybuf == bufA) ? bufB : bufA;
    }

    // ---- GCNConv + heads ----
    float* xw = ybuf;
    mm_kernel<<<WGRID, TPB, 0, stream>>>(xcur, W_gcn, xw, N);
    heads_kernel<<<WGRID, TPB, 0, stream>>>(rowptr, degi, srt, xw, dinv, b_gcn,
                                            W1, b1, W2, b2, out, N);
}

// Round 4
// 436.147 us; speedup vs baseline: 2.7580x; 1.3132x over previous
//
#include <hip/hip_runtime.h>
#include <hip/hip_bf16.h>

// GCNII fused, bf16 activations: CSR build + batched-gather layers.
// N=100000, E=1000000, F=64.
// Output: concat(out1 [N*4], out2 [N*3], h [N*64]) fp32.

#define TPB 256
typedef __hip_bfloat16 bf16;

// ---- degree count (int) ----
__global__ void deg_count_kernel(const int* __restrict__ col, int* __restrict__ degi, int E) {
    int e = blockIdx.x * blockDim.x + threadIdx.x;
    if (e < E) atomicAdd(&degi[col[e]], 1);
}

__global__ void dinv_kernel(const int* __restrict__ degi, float* __restrict__ dinv, int n) {
    int v = blockIdx.x * blockDim.x + threadIdx.x;
    if (v < n) dinv[v] = rsqrtf((float)degi[v] + 1.0f);  // +1 = self-loop
}

// ---- exclusive scan of degi -> rowptr (3-phase, chunks of 1024) ----
__global__ void scan_block_kernel(const int* __restrict__ degi, int* __restrict__ rowptr,
                                  int* __restrict__ blksum, int n) {
    __shared__ int s[256];
    int base = blockIdx.x * 1024;
    int t = threadIdx.x;
    int v[4]; int sum = 0;
#pragma unroll
    for (int i = 0; i < 4; ++i) {
        int idx = base + t * 4 + i;
        v[i] = (idx < n) ? degi[idx] : 0;
        sum += v[i];
    }
    s[t] = sum;
    __syncthreads();
    for (int off = 1; off < 256; off <<= 1) {
        int val = (t >= off) ? s[t - off] : 0;
        __syncthreads();
        s[t] += val;
        __syncthreads();
    }
    int excl = s[t] - sum;
    if (t == 255) blksum[blockIdx.x] = s[255];
    int run = excl;
#pragma unroll
    for (int i = 0; i < 4; ++i) {
        int idx = base + t * 4 + i;
        if (idx < n) rowptr[idx] = run;
        run += v[i];
    }
}

__global__ void scan_top_kernel(int* __restrict__ blksum, int* __restrict__ blkoff, int nblk) {
    __shared__ int s[256];
    int t = threadIdx.x;
    int mine = (t < nblk) ? blksum[t] : 0;
    s[t] = mine;
    __syncthreads();
    for (int off = 1; off < 256; off <<= 1) {
        int val = (t >= off) ? s[t - off] : 0;
        __syncthreads();
        s[t] += val;
        __syncthreads();
    }
    if (t < nblk) blkoff[t] = s[t] - mine;  // exclusive
}

__global__ void scan_add_kernel(int* __restrict__ rowptr, int* __restrict__ cursor,
                                const int* __restrict__ blkoff, int n) {
    int idx = blockIdx.x * blockDim.x + threadIdx.x;
    if (idx < n) {
        int val = rowptr[idx] + blkoff[idx >> 10];
        rowptr[idx] = val;
        cursor[idx] = val;
    }
}

// ---- scatter edges into dst-sorted buckets: srt[pos] = {row, dinv[r]*dinv[c]} ----
__global__ void scatter_kernel(const int* __restrict__ ei, const float* __restrict__ dinv,
                               int* __restrict__ cursor, int2* __restrict__ srt, int E) {
    int e = blockIdx.x * blockDim.x + threadIdx.x;
    if (e < E) {
        int r = ei[e];
        int c = ei[E + e];
        int pos = atomicAdd(&cursor[c], 1);
        int2 rec;
        rec.x = r;
        rec.y = __float_as_int(dinv[r] * dinv[c]);
        srt[pos] = rec;
    }
}

// ---- fp32 -> bf16 conversion (RNE) ----
__global__ void cvt_kernel(const float* __restrict__ x, bf16* __restrict__ xb, int n4) {
    int i = blockIdx.x * blockDim.x + threadIdx.x;
    if (i < n4) {
        float4 f = ((const float4*)x)[i];
        bf16 b0 = __float2bfloat16(f.x), b1 = __float2bfloat16(f.y);
        bf16 b2 = __float2bfloat16(f.z), b3 = __float2bfloat16(f.w);
        ushort4 u;
        u.x = *(unsigned short*)&b0; u.y = *(unsigned short*)&b1;
        u.z = *(unsigned short*)&b2; u.w = *(unsigned short*)&b3;
        ((ushort4*)xb)[i] = u;
    }
}

// ---- batched gather: sum over edges of w * xb[src][lane], rounds of 8 ----
__device__ __forceinline__ float gather8(const int2* __restrict__ srt, int beg, int end,
                                         const bf16* __restrict__ xb, int lane) {
    float a0 = 0.0f, a1 = 0.0f;
    for (int e = beg; e < end; e += 8) {
        float w[8]; int src[8];
#pragma unroll
        for (int i = 0; i < 8; ++i) {
            int idx = e + i;
            bool ok = idx < end;                  // wave-uniform
            int2 rr = srt[ok ? idx : beg];
            w[i] = ok ? __int_as_float(rr.y) : 0.0f;
            src[i] = rr.x;
        }
        float g[8];
#pragma unroll
        for (int i = 0; i < 8; ++i) g[i] = __bfloat162float(xb[(size_t)src[i] * 64 + lane]);
#pragma unroll
        for (int i = 0; i < 8; ++i) {
            if (i & 1) a1 = fmaf(w[i], g[i], a1);
            else       a0 = fmaf(w[i], g[i], a0);
        }
    }
    return a0 + a1;
}

// xor-swizzled LDS layout for W^T: quad (j, k4) lives at j*64 + ((k4 ^ (j&15))<<2)
__device__ __forceinline__ void stage_w(const float* __restrict__ W, float* __restrict__ Wsm) {
    for (int i = threadIdx.x; i < 4096; i += TPB) {
        int k = i >> 6, j = i & 63;
        Wsm[j * 64 + (((k >> 2) ^ (j & 15)) << 2) + (k & 3)] = W[i];
    }
}

__device__ __forceinline__ float mm64(const float* __restrict__ Wsm, const float* __restrict__ t,
                                      int lane) {
    float o = 0.0f;
#pragma unroll
    for (int k4 = 0; k4 < 16; ++k4) {
        float4 tt = *(const float4*)&t[k4 * 4];                               // broadcast
        float4 ww = *(const float4*)&Wsm[lane * 64 + ((k4 ^ (lane & 15)) << 2)];
        o = fmaf(tt.x, ww.x, o);
        o = fmaf(tt.y, ww.y, o);
        o = fmaf(tt.z, ww.z, o);
        o = fmaf(tt.w, ww.w, o);
    }
    return o;
}

// ---- fused GCN2Conv layer: y = relu( (0.9*(A_hat x) + 0.1*x) @ W ), bf16 in/out ----
__global__ __launch_bounds__(256) void layer_kernel(
        const int* __restrict__ rowptr, const int* __restrict__ degi,
        const int2* __restrict__ srt, const bf16* __restrict__ xb,
        const float* __restrict__ dinv, const float* __restrict__ W,
        bf16* __restrict__ yb, int n) {
    __shared__ __align__(16) float st[4][64];
    __shared__ __align__(16) float Wsm[4096];
    int wid = threadIdx.x >> 6;
    int lane = threadIdx.x & 63;
    stage_w(W, Wsm);
    __syncthreads();
    int stride = gridDim.x * 4;
    for (int v = blockIdx.x * 4 + wid; v < n; v += stride) {
        int beg = rowptr[v];
        int end = beg + degi[v];
        float acc = gather8(srt, beg, end, xb, lane);
        float xv = __bfloat162float(xb[(size_t)v * 64 + lane]);
        float d = dinv[v];
        float t = 0.9f * (acc + d * d * xv) + 0.1f * xv;
        st[wid][lane] = t;
        __builtin_amdgcn_wave_barrier();
        float o = mm64(Wsm, st[wid], lane);
        __builtin_amdgcn_wave_barrier();
        yb[(size_t)v * 64 + lane] = __float2bfloat16(fmaxf(o, 0.0f));
    }
}

// ---- plain matmul: y = x @ W_gcn (64x64), bf16 in/out ----
__global__ __launch_bounds__(256) void mm_kernel(
        const bf16* __restrict__ xb, const float* __restrict__ W,
        bf16* __restrict__ yb, int n) {
    __shared__ __align__(16) float st[4][64];
    __shared__ __align__(16) float Wsm[4096];
    int wid = threadIdx.x >> 6;
    int lane = threadIdx.x & 63;
    stage_w(W, Wsm);
    __syncthreads();
    int stride = gridDim.x * 4;
    for (int v = blockIdx.x * 4 + wid; v < n; v += stride) {
        st[wid][lane] = __bfloat162float(xb[(size_t)v * 64 + lane]);
        __builtin_amdgcn_wave_barrier();
        float o = mm64(Wsm, st[wid], lane);
        __builtin_amdgcn_wave_barrier();
        yb[(size_t)v * 64 + lane] = __float2bfloat16(o);
    }
}

// ---- final: h = gather(xw) + dinv^2*xw + b_gcn (fp32 out); out1/out2 via tiny heads ----
__global__ __launch_bounds__(256) void heads_kernel(
        const int* __restrict__ rowptr, const int* __restrict__ degi,
        const int2* __restrict__ srt, const bf16* __restrict__ xwb,
        const float* __restrict__ dinv, const float* __restrict__ bg,
        const float* __restrict__ W1, const float* __restrict__ b1,
        const float* __restrict__ W2, const float* __restrict__ b2,
        float* __restrict__ out, int n) {
    __shared__ __align__(16) float hs[4][64];
    __shared__ __align__(16) float whd[448];   // whd[j*64+k], j=0..6
    __shared__ float bs[8];
    int wid = threadIdx.x >> 6;
    int lane = threadIdx.x & 63;
    // FIX (round 3 bug): stage all 448 entries with a loop — blockDim is only 256,
    // so `if (threadIdx.x < 448)` left whd[256..447] (W2 columns!) uninitialized.
    for (int i = threadIdx.x; i < 448; i += TPB) {
        int j = i >> 6, k = i & 63;
        whd[i] = (j < 4) ? W1[k * 4 + j] : W2[k * 3 + (j - 4)];
    }
    if (threadIdx.x < 7) bs[threadIdx.x] = (threadIdx.x < 4) ? b1[threadIdx.x] : b2[threadIdx.x - 4];
    __syncthreads();
    int j = lane >> 3;            // output index handled by this 8-lane group
    int k0 = (lane & 7) * 8;      // k-slice for the partial dot
    int stride = gridDim.x * 4;
    for (int v = blockIdx.x * 4 + wid; v < n; v += stride) {
        int beg = rowptr[v];
        int end = beg + degi[v];
        float acc = gather8(srt, beg, end, xwb, lane);
        float d = dinv[v];
        float h = acc + d * d * __bfloat162float(xwb[(size_t)v * 64 + lane]) + bg[lane];
        out[(size_t)7 * n + (size_t)v * 64 + lane] = h;
        hs[wid][lane] = h;
        __builtin_amdgcn_wave_barrier();
        float part = 0.0f;
        if (j < 7) {
            float4 h0 = *(const float4*)&hs[wid][k0];
            float4 h1 = *(const float4*)&hs[wid][k0 + 4];
            const float4* wq = (const float4*)&whd[j * 64 + k0];
            float4 w0 = wq[0], w1 = wq[1];
            part = h0.x * w0.x + h0.y * w0.y + h0.z * w0.z + h0.w * w0.w
                 + h1.x * w1.x + h1.y * w1.y + h1.z * w1.z + h1.w * w1.w;
        }
        part += __shfl_down(part, 4);
        part += __shfl_down(part, 2);
        part += __shfl_down(part, 1);
        if ((lane & 7) == 0 && j < 7) {
            float s = bs[j] + part;
            if (j < 4) out[(size_t)v * 4 + j] = s;
            else       out[(size_t)4 * n + (size_t)v * 3 + (j - 4)] = s;
        }
        __builtin_amdgcn_wave_barrier();
    }
}

extern "C" void kernel_launch(void* const* d_in, const int* in_sizes, int n_in,
                              void* d_out, int out_size, void* d_ws, size_t ws_size,
                              hipStream_t stream) {
    const float* x     = (const float*)d_in[0];
    const int*   ei    = (const int*)d_in[1];
    const float* Ws    = (const float*)d_in[2];
    const float* W_gcn = (const float*)d_in[3];
    const float* b_gcn = (const float*)d_in[4];
    const float* W1    = (const float*)d_in[5];
    const float* b1    = (const float*)d_in[6];
    const float* W2    = (const float*)d_in[7];
    const float* b2    = (const float*)d_in[8];
    float* out = (float*)d_out;

    const int N = in_sizes[0] / 64;
    const int E = in_sizes[1] / 2;
    const int NLAYERS = in_sizes[2] / 4096;  // L-1 = 3

    // ws layout: degi[N] rowptr[N] cursor[N] blksum[256] blkoff[256] (int)
    //            dinv[N] (f32) | srt[E] (int2) | x0b, bufA, bufB (bf16 N*64 each)
    int*   degi   = (int*)d_ws;
    int*   rowptr = degi + N;
    int*   cursor = rowptr + N;
    int*   blksum = cursor + N;
    int*   blkoff = blksum + 256;
    float* dinv   = (float*)(blkoff + 256);
    int2*  srt    = (int2*)(dinv + N);
    bf16*  x0b    = (bf16*)(srt + E);
    bf16*  bufA   = x0b + (size_t)N * 64;
    bf16*  bufB   = bufA + (size_t)N * 64;

    const int nblk = (N + 1023) / 1024;
    const int grid_e = (E + TPB - 1) / TPB;
    const int grid_n = (N + TPB - 1) / TPB;
    const int WGRID = 4096;

    // ---- CSR build ----
    hipMemsetAsync(degi, 0, (size_t)N * sizeof(int), stream);
    deg_count_kernel<<<grid_e, TPB, 0, stream>>>(ei + E, degi, E);
    dinv_kernel<<<grid_n, TPB, 0, stream>>>(degi, dinv, N);
    scan_block_kernel<<<nblk, 256, 0, stream>>>(degi, rowptr, blksum, N);
    scan_top_kernel<<<1, 256, 0, stream>>>(blksum, blkoff, nblk);
    scan_add_kernel<<<grid_n, TPB, 0, stream>>>(rowptr, cursor, blkoff, N);
    scatter_kernel<<<grid_e, TPB, 0, stream>>>(ei, dinv, cursor, srt, E);
    cvt_kernel<<<(N * 16 + TPB - 1) / TPB, TPB, 0, stream>>>(x, x0b, N * 16);

    // ---- GCN2Conv layers ----
    const bf16* xcur = x0b;
    bf16* ybuf = bufA;
    for (int i = 0; i < NLAYERS; ++i) {
        layer_kernel<<<WGRID, TPB, 0, stream>>>(rowptr, degi, srt, xcur, dinv,
                                                Ws + (size_t)i * 4096, ybuf, N);
        xcur = ybuf;
        ybuf = (ybuf == bufA) ? bufB : bufA;
    }

    // ---- GCNConv + heads ----
    bf16* xw = ybuf;
    mm_kernel<<<WGRID, TPB, 0, stream>>>(xcur, W_gcn, xw, N);
    heads_kernel<<<WGRID, TPB, 0, stream>>>(rowptr, degi, srt, xw, dinv, b_gcn,
                                            W1, b1, W2, b2, out, N);
}

// Round 5
// 434.851 us; speedup vs baseline: 2.7663x; 1.0030x over previous
//
#include <hip/hip_runtime.h>
#include <hip/hip_bf16.h>

// GCNII fused, bf16 activations, scalarized CSR gather.
// N=100000, E=1000000, F=64.
// Output: concat(out1 [N*4], out2 [N*3], h [N*64]) fp32.

#define TPB 256
#define WROW 66   // W^T row stride in floats: 8B-aligned, bank-rotated (2j+k)
typedef __hip_bfloat16 bf16;

// ---- degree count (int) ----
__global__ void deg_count_kernel(const int* __restrict__ col, int* __restrict__ degi, int E) {
    int e = blockIdx.x * blockDim.x + threadIdx.x;
    if (e < E) atomicAdd(&degi[col[e]], 1);
}

__global__ void dinv_kernel(const int* __restrict__ degi, float* __restrict__ dinv, int n) {
    int v = blockIdx.x * blockDim.x + threadIdx.x;
    if (v < n) dinv[v] = rsqrtf((float)degi[v] + 1.0f);  // +1 = self-loop
}

// ---- exclusive scan of degi -> rowptr (3-phase, chunks of 1024) ----
__global__ void scan_block_kernel(const int* __restrict__ degi, int* __restrict__ rowptr,
                                  int* __restrict__ blksum, int n) {
    __shared__ int s[256];
    int base = blockIdx.x * 1024;
    int t = threadIdx.x;
    int v[4]; int sum = 0;
#pragma unroll
    for (int i = 0; i < 4; ++i) {
        int idx = base + t * 4 + i;
        v[i] = (idx < n) ? degi[idx] : 0;
        sum += v[i];
    }
    s[t] = sum;
    __syncthreads();
    for (int off = 1; off < 256; off <<= 1) {
        int val = (t >= off) ? s[t - off] : 0;
        __syncthreads();
        s[t] += val;
        __syncthreads();
    }
    int excl = s[t] - sum;
    if (t == 255) blksum[blockIdx.x] = s[255];
    int run = excl;
#pragma unroll
    for (int i = 0; i < 4; ++i) {
        int idx = base + t * 4 + i;
        if (idx < n) rowptr[idx] = run;
        run += v[i];
    }
}

__global__ void scan_top_kernel(int* __restrict__ blksum, int* __restrict__ blkoff, int nblk) {
    __shared__ int s[256];
    int t = threadIdx.x;
    int mine = (t < nblk) ? blksum[t] : 0;
    s[t] = mine;
    __syncthreads();
    for (int off = 1; off < 256; off <<= 1) {
        int val = (t >= off) ? s[t - off] : 0;
        __syncthreads();
        s[t] += val;
        __syncthreads();
    }
    if (t < nblk) blkoff[t] = s[t] - mine;  // exclusive
}

__global__ void scan_add_kernel(int* __restrict__ rowptr, int* __restrict__ cursor,
                                const int* __restrict__ blkoff, int n) {
    int idx = blockIdx.x * blockDim.x + threadIdx.x;
    if (idx < n) {
        int val = rowptr[idx] + blkoff[idx >> 10];
        rowptr[idx] = val;
        cursor[idx] = val;
    }
}

// ---- scatter edges into dst-sorted buckets: srt[pos] = {row, dinv[r]*dinv[c]} ----
__global__ void scatter_kernel(const int* __restrict__ ei, const float* __restrict__ dinv,
                               int* __restrict__ cursor, int2* __restrict__ srt, int E) {
    int e = blockIdx.x * blockDim.x + threadIdx.x;
    if (e < E) {
        int r = ei[e];
        int c = ei[E + e];
        int pos = atomicAdd(&cursor[c], 1);
        int2 rec;
        rec.x = r;
        rec.y = __float_as_int(dinv[r] * dinv[c]);
        srt[pos] = rec;
    }
}

// ---- fp32 -> bf16 conversion (RNE) ----
__global__ void cvt_kernel(const float* __restrict__ x, bf16* __restrict__ xb, int n4) {
    int i = blockIdx.x * blockDim.x + threadIdx.x;
    if (i < n4) {
        float4 f = ((const float4*)x)[i];
        bf16 b0 = __float2bfloat16(f.x), b1 = __float2bfloat16(f.y);
        bf16 b2 = __float2bfloat16(f.z), b3 = __float2bfloat16(f.w);
        ushort4 u;
        u.x = *(unsigned short*)&b0; u.y = *(unsigned short*)&b1;
        u.z = *(unsigned short*)&b2; u.w = *(unsigned short*)&b3;
        ((ushort4*)xb)[i] = u;
    }
}

// ---- scalarized gather: edge metadata via one vector load + v_readlane ----
// beg/end wave-uniform (SGPR). Per edge: scalar row base + scalar weight,
// so the load is s[base]+lane addressing and the fma takes an SGPR operand.
__device__ __forceinline__ float gather_scalar(const int2* __restrict__ srt, int beg, int end,
                                               const unsigned short* __restrict__ xb, int lane) {
    float acc = 0.0f;
    for (int base = beg; base < end; base += 64) {
        int nle = end - base;
        if (nle > 64) nle = 64;
        int2 m = srt[base + (lane < nle ? lane : nle - 1)];  // lane i = edge base+i
        int mx = m.x, my = m.y;
        for (int sub = 0; sub < nle; sub += 8) {             // wave-uniform trips
#pragma unroll
            for (int i = 0; i < 8; ++i) {
                int s_src = __builtin_amdgcn_readlane(mx, i);   // SGPR
                int s_w   = __builtin_amdgcn_readlane(my, i);   // SGPR
                float w = (sub + i < nle) ? __int_as_float(s_w) : 0.0f;  // s_cselect
                const unsigned short* rowp = xb + ((size_t)(unsigned)s_src << 6);
                float g = __int_as_float(((int)rowp[lane]) << 16);  // bf16 -> f32
                acc = fmaf(w, g, acc);
            }
            mx = __shfl_down(mx, 8);
            my = __shfl_down(my, 8);
        }
    }
    return acc;
}

// ---- stage W^T into LDS at row stride WROW: Wsm[j*WROW + k] = W[k*64 + j] ----
__device__ __forceinline__ void stage_w(const float* __restrict__ W, float* __restrict__ Wsm) {
    for (int i = threadIdx.x; i < 4096; i += TPB)
        Wsm[(i & 63) * WROW + (i >> 6)] = W[i];
}

// o[lane] = sum_k t[k] * W[k][lane]; all LDS reads use immediate offsets.
__device__ __forceinline__ float mm64(const float* __restrict__ Wsm, const float* __restrict__ t,
                                      int lane) {
    const float* wrow = &Wsm[lane * WROW];
    float o = 0.0f;
#pragma unroll
    for (int k4 = 0; k4 < 16; ++k4) {
        float4 tt = *(const float4*)(t + k4 * 4);          // b128 broadcast (free)
        float2 wa = *(const float2*)(wrow + k4 * 4);       // b64, bank-rotated
        float2 wb = *(const float2*)(wrow + k4 * 4 + 2);
        o = fmaf(tt.x, wa.x, o);
        o = fmaf(tt.y, wa.y, o);
        o = fmaf(tt.z, wb.x, o);
        o = fmaf(tt.w, wb.y, o);
    }
    return o;
}

// ---- fused GCN2Conv layer: y = relu( (0.9*(A_hat x) + 0.1*x) @ W ), bf16 in/out ----
__global__ __launch_bounds__(256) void layer_kernel(
        const int* __restrict__ rowptr, const int* __restrict__ degi,
        const int2* __restrict__ srt, const unsigned short* __restrict__ xb,
        const float* __restrict__ dinv, const float* __restrict__ W,
        unsigned short* __restrict__ yb, int n) {
    __shared__ __align__(16) float st[4][64];
    __shared__ __align__(16) float Wsm[64 * WROW];
    int wid = __builtin_amdgcn_readfirstlane(threadIdx.x >> 6);
    int lane = threadIdx.x & 63;
    stage_w(W, Wsm);
    __syncthreads();
    int stride = gridDim.x * 4;
    for (int v = blockIdx.x * 4 + wid; v < n; v += stride) {
        int beg = __builtin_amdgcn_readfirstlane(rowptr[v]);
        int deg = __builtin_amdgcn_readfirstlane(degi[v]);
        float acc = gather_scalar(srt, beg, beg + deg, xb, lane);
        const unsigned short* selfp = xb + ((size_t)(unsigned)v << 6);
        float xv = __int_as_float(((int)selfp[lane]) << 16);
        float d = dinv[v];
        float t = 0.9f * (acc + d * d * xv) + 0.1f * xv;
        st[wid][lane] = t;
        __builtin_amdgcn_wave_barrier();
        float o = mm64(Wsm, st[wid], lane);
        __builtin_amdgcn_wave_barrier();
        o = fmaxf(o, 0.0f);
        bf16 ob = __float2bfloat16(o);
        yb[(size_t)(unsigned)v * 64 + lane] = *(unsigned short*)&ob;
    }
}

// ---- plain matmul: y = x @ W_gcn (64x64), bf16 in/out ----
__global__ __launch_bounds__(256) void mm_kernel(
        const unsigned short* __restrict__ xb, const float* __restrict__ W,
        unsigned short* __restrict__ yb, int n) {
    __shared__ __align__(16) float st[4][64];
    __shared__ __align__(16) float Wsm[64 * WROW];
    int wid = __builtin_amdgcn_readfirstlane(threadIdx.x >> 6);
    int lane = threadIdx.x & 63;
    stage_w(W, Wsm);
    __syncthreads();
    int stride = gridDim.x * 4;
    for (int v = blockIdx.x * 4 + wid; v < n; v += stride) {
        const unsigned short* selfp = xb + ((size_t)(unsigned)v << 6);
        st[wid][lane] = __int_as_float(((int)selfp[lane]) << 16);
        __builtin_amdgcn_wave_barrier();
        float o = mm64(Wsm, st[wid], lane);
        __builtin_amdgcn_wave_barrier();
        bf16 ob = __float2bfloat16(o);
        yb[(size_t)(unsigned)v * 64 + lane] = *(unsigned short*)&ob;
    }
}

// ---- final: h = gather(xw) + dinv^2*xw + b_gcn (fp32 out); tiny heads ----
__global__ __launch_bounds__(256) void heads_kernel(
        const int* __restrict__ rowptr, const int* __restrict__ degi,
        const int2* __restrict__ srt, const unsigned short* __restrict__ xwb,
        const float* __restrict__ dinv, const float* __restrict__ bg,
        const float* __restrict__ W1, const float* __restrict__ b1,
        const float* __restrict__ W2, const float* __restrict__ b2,
        float* __restrict__ out, int n) {
    __shared__ __align__(16) float hs[4][64];
    __shared__ __align__(16) float whd[448];   // whd[j*64+k], j=0..6
    __shared__ float bs[8];
    int wid = __builtin_amdgcn_readfirstlane(threadIdx.x >> 6);
    int lane = threadIdx.x & 63;
    for (int i = threadIdx.x; i < 448; i += TPB) {   // loop: blockDim is 256 < 448
        int j = i >> 6, k = i & 63;
        whd[i] = (j < 4) ? W1[k * 4 + j] : W2[k * 3 + (j - 4)];
    }
    if (threadIdx.x < 7) bs[threadIdx.x] = (threadIdx.x < 4) ? b1[threadIdx.x] : b2[threadIdx.x - 4];
    __syncthreads();
    int j = lane >> 3;            // output index handled by this 8-lane group
    int k0 = (lane & 7) * 8;      // k-slice for the partial dot
    int stride = gridDim.x * 4;
    for (int v = blockIdx.x * 4 + wid; v < n; v += stride) {
        int beg = __builtin_amdgcn_readfirstlane(rowptr[v]);
        int deg = __builtin_amdgcn_readfirstlane(degi[v]);
        float acc = gather_scalar(srt, beg, beg + deg, xwb, lane);
        const unsigned short* selfp = xwb + ((size_t)(unsigned)v << 6);
        float xv = __int_as_float(((int)selfp[lane]) << 16);
        float d = dinv[v];
        float h = acc + d * d * xv + bg[lane];
        out[(size_t)7 * n + (size_t)(unsigned)v * 64 + lane] = h;
        hs[wid][lane] = h;
        __builtin_amdgcn_wave_barrier();
        float part = 0.0f;
        if (j < 7) {
            float4 h0 = *(const float4*)&hs[wid][k0];
            float4 h1 = *(const float4*)&hs[wid][k0 + 4];
            const float4* wq = (const float4*)&whd[j * 64 + k0];
            float4 w0 = wq[0], w1 = wq[1];
            part = h0.x * w0.x + h0.y * w0.y + h0.z * w0.z + h0.w * w0.w
                 + h1.x * w1.x + h1.y * w1.y + h1.z * w1.z + h1.w * w1.w;
        }
        part += __shfl_down(part, 4);
        part += __shfl_down(part, 2);
        part += __shfl_down(part, 1);
        if ((lane & 7) == 0 && j < 7) {
            float s = bs[j] + part;
            if (j < 4) out[(size_t)v * 4 + j] = s;
            else       out[(size_t)4 * n + (size_t)v * 3 + (j - 4)] = s;
        }
        __builtin_amdgcn_wave_barrier();
    }
}

extern "C" void kernel_launch(void* const* d_in, const int* in_sizes, int n_in,
                              void* d_out, int out_size, void* d_ws, size_t ws_size,
                              hipStream_t stream) {
    const float* x     = (const float*)d_in[0];
    const int*   ei    = (const int*)d_in[1];
    const float* Ws    = (const float*)d_in[2];
    const float* W_gcn = (const float*)d_in[3];
    const float* b_gcn = (const float*)d_in[4];
    const float* W1    = (const float*)d_in[5];
    const float* b1    = (const float*)d_in[6];
    const float* W2    = (const float*)d_in[7];
    const float* b2    = (const float*)d_in[8];
    float* out = (float*)d_out;

    const int N = in_sizes[0] / 64;
    const int E = in_sizes[1] / 2;
    const int NLAYERS = in_sizes[2] / 4096;  // L-1 = 3

    // ws layout: degi[N] rowptr[N] cursor[N] blksum[256] blkoff[256] (int)
    //            dinv[N] (f32) | srt[E] (int2) | x0b, bufA, bufB (bf16 N*64 each)
    int*   degi   = (int*)d_ws;
    int*   rowptr = degi + N;
    int*   cursor = rowptr + N;
    int*   blksum = cursor + N;
    int*   blkoff = blksum + 256;
    float* dinv   = (float*)(blkoff + 256);
    int2*  srt    = (int2*)(dinv + N);
    unsigned short* x0b  = (unsigned short*)(srt + E);
    unsigned short* bufA = x0b + (size_t)N * 64;
    unsigned short* bufB = bufA + (size_t)N * 64;

    const int nblk = (N + 1023) / 1024;
    const int grid_e = (E + TPB - 1) / TPB;
    const int grid_n = (N + TPB - 1) / TPB;
    const int WGRID = 4096;

    // ---- CSR build ----
    hipMemsetAsync(degi, 0, (size_t)N * sizeof(int), stream);
    deg_count_kernel<<<grid_e, TPB, 0, stream>>>(ei + E, degi, E);
    dinv_kernel<<<grid_n, TPB, 0, stream>>>(degi, dinv, N);
    scan_block_kernel<<<nblk, 256, 0, stream>>>(degi, rowptr, blksum, N);
    scan_top_kernel<<<1, 256, 0, stream>>>(blksum, blkoff, nblk);
    scan_add_kernel<<<grid_n, TPB, 0, stream>>>(rowptr, cursor, blkoff, N);
    scatter_kernel<<<grid_e, TPB, 0, stream>>>(ei, dinv, cursor, srt, E);
    cvt_kernel<<<(N * 16 + TPB - 1) / TPB, TPB, 0, stream>>>(x, (bf16*)x0b, N * 16);

    // ---- GCN2Conv layers ----
    const unsigned short* xcur = x0b;
    unsigned short* ybuf = bufA;
    for (int i = 0; i < NLAYERS; ++i) {
        layer_kernel<<<WGRID, TPB, 0, stream>>>(rowptr, degi, srt, xcur, dinv,
                                                Ws + (size_t)i * 4096, ybuf, N);
        xcur = ybuf;
        ybuf = (ybuf == bufA) ? bufB : bufA;
    }

    // ---- GCNConv + heads ----
    unsigned short* xw = ybuf;
    mm_kernel<<<WGRID, TPB, 0, stream>>>(xcur, W_gcn, xw, N);
    heads_kernel<<<WGRID, TPB, 0, stream>>>(rowptr, degi, srt, xw, dinv, b_gcn,
                                            W1, b1, W2, b2, out, N);
}